// Round 6
// baseline (11.910 us; speedup 1.0000x reference)
//
#include <hip/hip_runtime.h>
#include <math.h>

#define THREADS 512
#define WAVES_PER_BLOCK (THREADS / 64)
#define PIX_PER_WAVE 8
#define IMG_W 128
#define IMG_H 128
#define SUBS 64           // faces strided across the 64 lanes of a wave

__device__ __forceinline__ float waveProd64(float v) {
    v *= __shfl_xor(v, 1);
    v *= __shfl_xor(v, 2);
    v *= __shfl_xor(v, 4);
    v *= __shfl_xor(v, 8);
    v *= __shfl_xor(v, 16);
    v *= __shfl_xor(v, 32);
    return v;
}

__global__ __launch_bounds__(THREADS)
void render_mask_fused8_kernel(const float* __restrict__ verts,
                               const int*   __restrict__ faces,
                               const float* __restrict__ focal,
                               const float* __restrict__ princ,
                               float* __restrict__ out,
                               int F, int niter)
{
    const int tid  = threadIdx.x;
    const int lane = tid & 63;
    const int wave = tid >> 6;                                  // 0..7
    const int pixBase = (blockIdx.x * WAVES_PER_BLOCK + wave) * PIX_PER_WAVE;

    const int c0 = pixBase & (IMG_W - 1);   // 8 consecutive columns, same row
    const int rr = pixBase >> 7;

    const float fclx = focal[0] * (2.0f / 128.0f);
    const float fcly = focal[1] * (2.0f / 128.0f);
    const float prx  = -(princ[0] - 64.0f) * (2.0f / 128.0f);
    const float pry  = -(princ[1] - 64.0f) * (2.0f / 128.0f);

    const float px0 = 1.0f - (2.0f * (float)c0 + 1.0f) * (1.0f / 128.0f);
    const float py  = 1.0f - (2.0f * (float)rr + 1.0f) * (1.0f / 128.0f);
    const float DX  = -2.0f / 128.0f;

    const float BLURF = 9.2102403669758494e-04f;  // log(1/1e-4 - 1) * 1e-4
    const float INV_SIGMA = 1.0e4f;
    const float EPS = 1e-25f;

    float prod[PIX_PER_WAVE];
#pragma unroll
    for (int k = 0; k < PIX_PER_WAVE; ++k) prod[k] = 1.0f;

    for (int it = 0; it < niter; ++it) {
        const int f = it * SUBS + lane;

        // ---- inline face build (per lane), shared by 8 pixels ----
        float v0x, v0y, v1x, v1y, v2x, v2y;
        bool dummy = (f >= F);
        if (!dummy) {
            const int i0 = faces[3 * f + 0];
            const int i1 = faces[3 * f + 1];
            const int i2 = faces[3 * f + 2];
            const float x0 = verts[3 * i0], y0 = verts[3 * i0 + 1], z0 = verts[3 * i0 + 2];
            const float x1 = verts[3 * i1], y1 = verts[3 * i1 + 1], z1 = verts[3 * i1 + 2];
            const float x2 = verts[3 * i2], y2 = verts[3 * i2 + 1], z2 = verts[3 * i2 + 2];
            const float rz0 = __builtin_amdgcn_rcpf(z0);
            const float rz1 = __builtin_amdgcn_rcpf(z1);
            const float rz2 = __builtin_amdgcn_rcpf(z2);
            v0x = -fclx * (x0 * rz0) + prx;
            v0y = -fcly * (y0 * rz0) + pry;
            v1x = -fclx * (x1 * rz1) + prx;
            v1y = -fcly * (y1 * rz1) + pry;
            v2x = -fclx * (x2 * rz2) + prx;
            v2y = -fcly * (y2 * rz2) + pry;
            if (!(fminf(fminf(z0, z1), z2) > 0.01f)) dummy = true;
        }
        if (dummy) {
            // far tiny triangle: inside=false, m2 huge -> q = 1 exactly
            v0x = 1000.0f;  v0y = 1000.0f;
            v1x = 1000.01f; v1y = 1000.0f;
            v2x = 1000.0f;  v2y = 1000.01f;
        }

        const float e01x = v1x - v0x, e01y = v1y - v0y;
        const float e12x = v2x - v1x, e12y = v2y - v1y;
        const float e20x = v0x - v2x, e20y = v0y - v2y;
        const float area = e01x * (v2y - v0y) - e01y * (v2x - v0x);

        const float inv01 = __builtin_amdgcn_rcpf(fmaxf(e01x * e01x + e01y * e01y, 1e-12f));
        const float inv12 = __builtin_amdgcn_rcpf(fmaxf(e12x * e12x + e12y * e12y, 1e-12f));
        const float inv20 = __builtin_amdgcn_rcpf(fmaxf(e20x * e20x + e20y * e20y, 1e-12f));

        // ---- y-dependent terms shared by all 8 pixels (same row) ----
        const float d0y = py - v0y;
        const float d1y = d0y - e01y;
        const float d2y = d0y + e20y;
        const float a0  = e12x * d1y;
        const float a1  = e20x * d2y;
        const float a2  = e01x * d0y;
        const float b01 = d0y * e01y;
        const float b12 = d1y * e12y;
        const float b20 = d2y * e20y;

#pragma unroll
        for (int k = 0; k < PIX_PER_WAVE; ++k) {
            const float pxk = px0 + (float)k * DX;
            const float d0x = pxk - v0x;
            const float d1x = d0x - e01x;
            const float d2x = d0x + e20x;
            const float w0 = a0 - e12y * d1x;
            const float w1 = a1 - e20y * d2x;
            const float w2 = a2 - e01y * d0x;
            const bool inside = (w0 * area >= 0.0f) && (w1 * area >= 0.0f) &&
                                (w2 * area >= 0.0f);
            float t, rx, ry, m2;
            t  = fminf(fmaxf((d0x * e01x + b01) * inv01, 0.0f), 1.0f);
            rx = d0x - t * e01x; ry = d0y - t * e01y;
            m2 = rx * rx + ry * ry;
            t  = fminf(fmaxf((d1x * e12x + b12) * inv12, 0.0f), 1.0f);
            rx = d1x - t * e12x; ry = d1y - t * e12y;
            m2 = fminf(m2, rx * rx + ry * ry);
            t  = fminf(fmaxf((d2x * e20x + b20) * inv20, 0.0f), 1.0f);
            rx = d2x - t * e20x; ry = d2y - t * e20y;
            m2 = fminf(m2, rx * rx + ry * ry);
            const float s = inside ? -m2 : m2;
            const float e = __expf(fminf(s, BLURF) * INV_SIGMA);
            const float q = (s <= BLURF) ? (e * __builtin_amdgcn_rcpf(1.0f + e))
                                         : 1.0f;
            prod[k] *= q;
        }

        // exit when every pixel's wave-product is provably < EPS:
        // q in [0,1] => wave product <= min lane prod, so any-lane < EPS suffices.
        bool alldone = true;
#pragma unroll
        for (int k = 0; k < PIX_PER_WAVE; ++k) {
            alldone = alldone & __any(prod[k] < EPS);
        }
        if (alldone) break;
    }

    // saturated pixels round to exactly 1.0f; only reduce the rest (wave-uniform branch)
#pragma unroll
    for (int k = 0; k < PIX_PER_WAVE; ++k) {
        float t = 1.0f;
        if (!__any(prod[k] < EPS)) {
            t = 1.0f - waveProd64(prod[k]);
        }
        if (lane == 0) out[pixBase + k] = t;
    }
}

extern "C" void kernel_launch(void* const* d_in, const int* in_sizes, int n_in,
                              void* d_out, int out_size, void* d_ws, size_t ws_size,
                              hipStream_t stream) {
    const float* verts = (const float*)d_in[0];
    const int*   faces = (const int*)d_in[1];
    const float* focal = (const float*)d_in[2];
    const float* princ = (const float*)d_in[3];
    float* out = (float*)d_out;

    const int F = in_sizes[1] / 3;
    const int niter = (F + SUBS - 1) / SUBS;

    const int pixels = IMG_W * IMG_H;
    const int blocks = pixels / (WAVES_PER_BLOCK * PIX_PER_WAVE);   // 256
    hipLaunchKernelGGL(render_mask_fused8_kernel, dim3(blocks), dim3(THREADS), 0, stream,
                       verts, faces, focal, princ, out, F, niter);
}

// Round 7
// 10.552 us; speedup vs baseline: 1.1286x; 1.1286x over previous
//
#include <hip/hip_runtime.h>
#include <math.h>

#define THREADS 1024
#define WAVES_PER_BLOCK (THREADS / 64)
#define PIX_PER_WAVE 4
#define IMG_W 128
#define IMG_H 128
#define SUBS 64           // faces strided across the 64 lanes of a wave

__device__ __forceinline__ float waveProd64(float v) {
    v *= __shfl_xor(v, 1);
    v *= __shfl_xor(v, 2);
    v *= __shfl_xor(v, 4);
    v *= __shfl_xor(v, 8);
    v *= __shfl_xor(v, 16);
    v *= __shfl_xor(v, 32);
    return v;
}

__global__ __launch_bounds__(THREADS)
void render_mask_fused4s_kernel(const float* __restrict__ verts,
                                const int*   __restrict__ faces,
                                const float* __restrict__ focal,
                                const float* __restrict__ princ,
                                float* __restrict__ out,
                                int F, int niter)
{
    const int tid  = threadIdx.x;
    const int lane = tid & 63;
    const int wave = tid >> 6;                                  // 0..15
    const int pixBase = (blockIdx.x * WAVES_PER_BLOCK + wave) * PIX_PER_WAVE;

    const int c0 = pixBase & (IMG_W - 1);   // 4 consecutive columns, same row
    const int rr = pixBase >> 7;

    const float fclx = focal[0] * (2.0f / 128.0f);
    const float fcly = focal[1] * (2.0f / 128.0f);
    const float prx  = -(princ[0] - 64.0f) * (2.0f / 128.0f);
    const float pry  = -(princ[1] - 64.0f) * (2.0f / 128.0f);

    const float px0 = 1.0f - (2.0f * (float)c0 + 1.0f) * (1.0f / 128.0f);
    const float py  = 1.0f - (2.0f * (float)rr + 1.0f) * (1.0f / 128.0f);
    const float DX  = -2.0f / 128.0f;
    const float px1 = px0 + DX, px2 = px0 + 2.0f * DX, px3 = px0 + 3.0f * DX;

    const float BLURF = 9.2102403669758494e-04f;  // log(1/1e-4 - 1) * 1e-4
    const float INV_SIGMA = 1.0e4f;
    const float EPS = 1e-25f;

    float prod0 = 1.0f, prod1 = 1.0f, prod2 = 1.0f, prod3 = 1.0f;
    // wave-uniform "saturated" flags: once any lane's partial product < EPS,
    // the wave product is provably < EPS (q in [0,1]) and output rounds to 1.0f
    bool done0 = false, done1 = false, done2 = false, done3 = false;

    for (int it = 0; it < niter; ++it) {
        const int f = it * SUBS + lane;

        // ---- inline face build (per lane), shared by active pixels ----
        float v0x, v0y, v1x, v1y, v2x, v2y;
        bool dummy = (f >= F);
        if (!dummy) {
            const int i0 = faces[3 * f + 0];
            const int i1 = faces[3 * f + 1];
            const int i2 = faces[3 * f + 2];
            const float x0 = verts[3 * i0], y0 = verts[3 * i0 + 1], z0 = verts[3 * i0 + 2];
            const float x1 = verts[3 * i1], y1 = verts[3 * i1 + 1], z1 = verts[3 * i1 + 2];
            const float x2 = verts[3 * i2], y2 = verts[3 * i2 + 1], z2 = verts[3 * i2 + 2];
            const float rz0 = __builtin_amdgcn_rcpf(z0);
            const float rz1 = __builtin_amdgcn_rcpf(z1);
            const float rz2 = __builtin_amdgcn_rcpf(z2);
            v0x = -fclx * (x0 * rz0) + prx;
            v0y = -fcly * (y0 * rz0) + pry;
            v1x = -fclx * (x1 * rz1) + prx;
            v1y = -fcly * (y1 * rz1) + pry;
            v2x = -fclx * (x2 * rz2) + prx;
            v2y = -fcly * (y2 * rz2) + pry;
            if (!(fminf(fminf(z0, z1), z2) > 0.01f)) dummy = true;
        }
        if (dummy) {
            // far tiny triangle: inside=false, m2 huge -> q = 1 exactly
            v0x = 1000.0f;  v0y = 1000.0f;
            v1x = 1000.01f; v1y = 1000.0f;
            v2x = 1000.0f;  v2y = 1000.01f;
        }

        const float e01x = v1x - v0x, e01y = v1y - v0y;
        const float e12x = v2x - v1x, e12y = v2y - v1y;
        const float e20x = v0x - v2x, e20y = v0y - v2y;
        const float area = e01x * (v2y - v0y) - e01y * (v2x - v0x);

        const float inv01 = __builtin_amdgcn_rcpf(fmaxf(e01x * e01x + e01y * e01y, 1e-12f));
        const float inv12 = __builtin_amdgcn_rcpf(fmaxf(e12x * e12x + e12y * e12y, 1e-12f));
        const float inv20 = __builtin_amdgcn_rcpf(fmaxf(e20x * e20x + e20y * e20y, 1e-12f));

        // ---- y-dependent terms shared by all 4 pixels (same row) ----
        const float d0y = py - v0y;
        const float d1y = d0y - e01y;
        const float d2y = d0y + e20y;
        const float a0  = e12x * d1y;
        const float a1  = e20x * d2y;
        const float a2  = e01x * d0y;
        const float b01 = d0y * e01y;
        const float b12 = d1y * e12y;
        const float b20 = d2y * e20y;

#define EVAL_PIXEL(PX, PROD, DONE)                                                \
        if (!(DONE)) {                                                            \
            const float d0x = (PX) - v0x;                                         \
            const float d1x = d0x - e01x;                                         \
            const float d2x = d0x + e20x;                                         \
            const float w0 = a0 - e12y * d1x;                                     \
            const float w1 = a1 - e20y * d2x;                                     \
            const float w2 = a2 - e01y * d0x;                                     \
            const bool inside = (w0 * area >= 0.0f) && (w1 * area >= 0.0f) &&     \
                                (w2 * area >= 0.0f);                              \
            float t, rx, ry, m2;                                                  \
            t  = fminf(fmaxf((d0x * e01x + b01) * inv01, 0.0f), 1.0f);            \
            rx = d0x - t * e01x; ry = d0y - t * e01y;                             \
            m2 = rx * rx + ry * ry;                                               \
            t  = fminf(fmaxf((d1x * e12x + b12) * inv12, 0.0f), 1.0f);            \
            rx = d1x - t * e12x; ry = d1y - t * e12y;                             \
            m2 = fminf(m2, rx * rx + ry * ry);                                    \
            t  = fminf(fmaxf((d2x * e20x + b20) * inv20, 0.0f), 1.0f);            \
            rx = d2x - t * e20x; ry = d2y - t * e20y;                             \
            m2 = fminf(m2, rx * rx + ry * ry);                                    \
            const float s = inside ? -m2 : m2;                                    \
            const float e = __expf(fminf(s, BLURF) * INV_SIGMA);                  \
            const float q = (s <= BLURF) ? (e * __builtin_amdgcn_rcpf(1.0f + e))  \
                                         : 1.0f;                                  \
            (PROD) *= q;                                                          \
            (DONE) = __any((PROD) < EPS);                                         \
        }

        EVAL_PIXEL(px0, prod0, done0)
        EVAL_PIXEL(px1, prod1, done1)
        EVAL_PIXEL(px2, prod2, done2)
        EVAL_PIXEL(px3, prod3, done3)
#undef EVAL_PIXEL

        if (done0 & done1 & done2 & done3) break;
    }

    // saturated pixels round to exactly 1.0f; only reduce the rest
    const float t0 = done0 ? 1.0f : (1.0f - waveProd64(prod0));
    const float t1 = done1 ? 1.0f : (1.0f - waveProd64(prod1));
    const float t2 = done2 ? 1.0f : (1.0f - waveProd64(prod2));
    const float t3 = done3 ? 1.0f : (1.0f - waveProd64(prod3));

    if (lane == 0) {
        out[pixBase + 0] = t0;
        out[pixBase + 1] = t1;
        out[pixBase + 2] = t2;
        out[pixBase + 3] = t3;
    }
}

extern "C" void kernel_launch(void* const* d_in, const int* in_sizes, int n_in,
                              void* d_out, int out_size, void* d_ws, size_t ws_size,
                              hipStream_t stream) {
    const float* verts = (const float*)d_in[0];
    const int*   faces = (const int*)d_in[1];
    const float* focal = (const float*)d_in[2];
    const float* princ = (const float*)d_in[3];
    float* out = (float*)d_out;

    const int F = in_sizes[1] / 3;
    const int niter = (F + SUBS - 1) / SUBS;

    const int pixels = IMG_W * IMG_H;
    const int blocks = pixels / (WAVES_PER_BLOCK * PIX_PER_WAVE);   // 256
    hipLaunchKernelGGL(render_mask_fused4s_kernel, dim3(blocks), dim3(THREADS), 0, stream,
                       verts, faces, focal, princ, out, F, niter);
}